// Round 2
// baseline (11982.777 us; speedup 1.0000x reference)
//
#include <hip/hip_runtime.h>
#include <hip/hip_bf16.h>
#include <math.h>

// Problem constants
#define BB 2
#define SS 2048
#define DD 2048
#define HH 16
#define NOPE 128
#define ROPE 64
#define VDIM 128
#define KV_RANK 512
#define Q_RANK 1536
#define EPS 1e-6f
#define THETA 10000.0f

#define MROWS (BB*SS)          // 4096
#define QDIM (HH*(NOPE+ROPE))  // 3072
#define KVDIM (HH*(NOPE+VDIM)) // 4096
#define CKV_COLS (KV_RANK+ROPE) // 576

// ---------- generic tiled GEMM: C(M,N) = A(M,K) @ B(K,N), fp32 ----------
__global__ void gemm32(const float* __restrict__ A, const float* __restrict__ B,
                       float* __restrict__ C, int M, int N, int K) {
    __shared__ float As[32][33];
    __shared__ float Bs[32][33];
    int tx = threadIdx.x, ty = threadIdx.y;
    int tid = ty * 16 + tx;
    int bm = blockIdx.y * 32, bn = blockIdx.x * 32;
    float acc00 = 0.f, acc01 = 0.f, acc10 = 0.f, acc11 = 0.f;
    for (int k0 = 0; k0 < K; k0 += 32) {
        for (int idx = tid; idx < 32 * 32; idx += 256) {
            int r = idx >> 5, c = idx & 31;
            int gr = bm + r, gc = k0 + c;
            As[r][c] = (gr < M && gc < K) ? A[(size_t)gr * K + gc] : 0.f;
            int br = k0 + r, bc = bn + c;
            Bs[r][c] = (br < K && bc < N) ? B[(size_t)br * N + bc] : 0.f;
        }
        __syncthreads();
#pragma unroll
        for (int kk = 0; kk < 32; kk++) {
            float a0 = As[ty][kk], a1 = As[ty + 16][kk];
            float b0 = Bs[kk][tx], b1 = Bs[kk][tx + 16];
            acc00 += a0 * b0; acc01 += a0 * b1;
            acc10 += a1 * b0; acc11 += a1 * b1;
        }
        __syncthreads();
    }
    int r0 = bm + ty, r1 = bm + ty + 16, c0 = bn + tx, c1 = bn + tx + 16;
    if (r0 < M && c0 < N) C[(size_t)r0 * N + c0] = acc00;
    if (r0 < M && c1 < N) C[(size_t)r0 * N + c1] = acc01;
    if (r1 < M && c0 < N) C[(size_t)r1 * N + c0] = acc10;
    if (r1 < M && c1 < N) C[(size_t)r1 * N + c1] = acc11;
}

// ---------- RMSNorm (optionally in-place): out = in * rsqrt(mean(in^2)+eps) * w ----------
__global__ void rmsnorm_k(const float* __restrict__ in, int in_stride, int ncols,
                          const float* __restrict__ w,
                          float* __restrict__ out, int out_stride) {
    __shared__ float red[256];
    int row = blockIdx.x, tid = threadIdx.x;
    const float* rp = in + (size_t)row * in_stride;
    float s = 0.f;
    for (int c = tid; c < ncols; c += 256) { float v = rp[c]; s += v * v; }
    red[tid] = s;
    __syncthreads();
    for (int off = 128; off > 0; off >>= 1) {
        if (tid < off) red[tid] += red[tid + off];
        __syncthreads();
    }
    float scale = rsqrtf(red[0] / (float)ncols + EPS);
    float* op = out + (size_t)row * out_stride;
    for (int c = tid; c < ncols; c += 256)
        op[c] = rp[c] * scale * w[c];
}

// ---------- RoPE on q_pe: q layout (B,S,H,192), in-place on last 64 dims ----------
__global__ void rope_q_k(float* __restrict__ q) {
    int idx = blockIdx.x;              // (b*S+s)*H + h
    int pos = (idx / HH) % SS;
    float* pe = q + (size_t)idx * (NOPE + ROPE) + NOPE;
    int i = threadIdx.x;               // 0..31
    float inv = powf(THETA, -(float)i / 32.0f);
    float ang = (float)pos * inv;
    float c = cosf(ang), sn = sinf(ang);
    float x1 = pe[i], x2 = pe[i + 32];
    pe[i] = x1 * c - x2 * sn;
    pe[i + 32] = x2 * c + x1 * sn;
}

// ---------- RoPE on k_pe: ckv layout (B*S, 576), cols 512..575 in-place ----------
__global__ void rope_kpe_k(float* __restrict__ ckv) {
    int row = blockIdx.x;              // b*S + s
    int pos = row % SS;
    float* pe = ckv + (size_t)row * CKV_COLS + KV_RANK;
    int i = threadIdx.x;               // 0..31
    float inv = powf(THETA, -(float)i / 32.0f);
    float ang = (float)pos * inv;
    float c = cosf(ang), sn = sinf(ang);
    float x1 = pe[i], x2 = pe[i + 32];
    pe[i] = x1 * c - x2 * sn;
    pe[i + 32] = x2 * c + x1 * sn;
}

// ---------- Attention: one block per (b, h, q). Causal softmax(q·k)·v ----------
__global__ void attn_k(const float* __restrict__ q, const float* __restrict__ kv,
                       const float* __restrict__ ckv, float* __restrict__ o) {
    __shared__ float q_s[NOPE + ROPE];
    __shared__ float sc[SS];
    __shared__ float red[256];
    const float scale = 0.07216878364870322f; // 1/sqrt(192)

    int tid = threadIdx.x;
    int qi = blockIdx.x, h = blockIdx.y, b = blockIdx.z;

    const float* qrow = q + ((size_t)(b * SS + qi) * HH + h) * (NOPE + ROPE);
    for (int d = tid; d < NOPE + ROPE; d += 256) q_s[d] = qrow[d];
    __syncthreads();

    int L = qi + 1;
    float lmax = -1e30f;
    for (int j = tid; j < L; j += 256) {
        const float* kn = kv + ((size_t)(b * SS + j) * HH + h) * (NOPE + VDIM);
        const float* kp = ckv + (size_t)(b * SS + j) * CKV_COLS + KV_RANK;
        float s = 0.f;
#pragma unroll 8
        for (int d = 0; d < NOPE; d++) s += q_s[d] * kn[d];
#pragma unroll 8
        for (int d = 0; d < ROPE; d++) s += q_s[NOPE + d] * kp[d];
        s *= scale;
        sc[j] = s;
        lmax = fmaxf(lmax, s);
    }
    red[tid] = lmax;
    __syncthreads();
    for (int off = 128; off > 0; off >>= 1) {
        if (tid < off) red[tid] = fmaxf(red[tid], red[tid + off]);
        __syncthreads();
    }
    float m = red[0];
    __syncthreads();

    float lsum = 0.f;
    for (int j = tid; j < L; j += 256) {
        float e = expf(sc[j] - m);
        sc[j] = e;
        lsum += e;
    }
    red[tid] = lsum;
    __syncthreads();
    for (int off = 128; off > 0; off >>= 1) {
        if (tid < off) red[tid] += red[tid + off];
        __syncthreads();
    }
    float denom = red[0];
    __syncthreads();

    // o accumulation: 2 groups of 128 threads; thread owns v-dim d, group g takes keys j%2==g
    int d = tid & 127, g = tid >> 7;
    float acc = 0.f;
    for (int j = g; j < L; j += 2) {
        acc += sc[j] * kv[((size_t)(b * SS + j) * HH + h) * (NOPE + VDIM) + NOPE + d];
    }
    red[tid] = acc;
    __syncthreads();
    if (tid < 128) {
        float oval = (red[tid] + red[tid + 128]) / denom;
        o[(size_t)(b * SS + qi) * (HH * VDIM) + h * VDIM + tid] = oval;
    }
}

extern "C" void kernel_launch(void* const* d_in, const int* in_sizes, int n_in,
                              void* d_out, int out_size, void* d_ws, size_t ws_size,
                              hipStream_t stream) {
    const float* x        = (const float*)d_in[0];
    const float* w_dq     = (const float*)d_in[1];
    const float* q_a_norm = (const float*)d_in[2];
    const float* w_uq     = (const float*)d_in[3];
    const float* w_dkv    = (const float*)d_in[4];
    const float* kv_a_nrm = (const float*)d_in[5];
    const float* w_ukv    = (const float*)d_in[6];
    const float* w_o      = (const float*)d_in[7];
    float* out = (float*)d_out;

    float* ws = (float*)d_ws;
    float* q_lat = ws;                               // 4096*1536
    float* q     = q_lat + (size_t)MROWS * Q_RANK;   // 4096*3072
    float* ckv   = q + (size_t)MROWS * QDIM;         // 4096*576
    float* kv    = ckv + (size_t)MROWS * CKV_COLS;   // 4096*4096
    float* ao    = kv + (size_t)MROWS * KVDIM;       // 4096*2048

    dim3 blk(16, 16);

    // 1. q_lat = x @ w_dq
    gemm32<<<dim3(Q_RANK / 32, MROWS / 32), blk, 0, stream>>>(
        x, w_dq, q_lat, MROWS, Q_RANK, DD);
    // 2. rmsnorm(q_lat) in-place
    rmsnorm_k<<<MROWS, 256, 0, stream>>>(q_lat, Q_RANK, Q_RANK, q_a_norm, q_lat, Q_RANK);
    // 3. q = q_lat @ w_uq
    gemm32<<<dim3(QDIM / 32, MROWS / 32), blk, 0, stream>>>(
        q_lat, w_uq, q, MROWS, QDIM, Q_RANK);
    // 4. ckv = x @ w_dkv
    gemm32<<<dim3(CKV_COLS / 32 + 1, MROWS / 32), blk, 0, stream>>>(
        x, w_dkv, ckv, MROWS, CKV_COLS, DD);
    // 5. rmsnorm(ckv[:, :512]) in-place (k_pe cols 512..575 untouched)
    rmsnorm_k<<<MROWS, 256, 0, stream>>>(ckv, CKV_COLS, KV_RANK, kv_a_nrm, ckv, CKV_COLS);
    // 6. kv = rmsnormed-ckv[:, :512] @ w_ukv   (A rows have stride CKV_COLS)
    //    Use a strided view by passing K=KV_RANK but row stride CKV_COLS:
    //    easiest: treat A as MROWS x KV_RANK with lda=CKV_COLS via a copy-free trick
    //    -> gemm32 assumes lda==K, so do a strided copy first into 'ao' (free scratch).
    {
        // pack ckv[:, :512] into contiguous buffer (reuse 'ao' scratch before attention)
        // simple elementwise kernel via gemm-free path: use hipMemcpy2DAsync
        hipMemcpy2DAsync(ao, KV_RANK * sizeof(float),
                         ckv, CKV_COLS * sizeof(float),
                         KV_RANK * sizeof(float), MROWS,
                         hipMemcpyDeviceToDevice, stream);
        gemm32<<<dim3(KVDIM / 32, MROWS / 32), blk, 0, stream>>>(
            ao, w_ukv, kv, MROWS, KVDIM, KV_RANK);
    }
    // 7. RoPE in-place
    rope_q_k<<<MROWS * HH, 32, 0, stream>>>(q);
    rope_kpe_k<<<MROWS, 32, 0, stream>>>(ckv);
    // 8. attention
    attn_k<<<dim3(SS, HH, BB), 256, 0, stream>>>(q, kv, ckv, ao);
    // 9. out = ao @ w_o
    gemm32<<<dim3(DD / 32, MROWS / 32), blk, 0, stream>>>(
        ao, w_o, out, MROWS, DD, DD);
}

// Round 3
// 540.174 us; speedup vs baseline: 22.1832x; 22.1832x over previous
//
#include <hip/hip_runtime.h>
#include <hip/hip_bf16.h>
#include <math.h>

#define BB 2
#define SS 2048
#define DDIM 2048
#define HH 16
#define NOPE 128
#define ROPE_D 64
#define VD 128
#define KVR 512
#define QR 1536
#define EPSF 1e-6f
#define THETA 10000.0f
#define MR (BB*SS)            // 4096 rows (tokens)

typedef unsigned short u16;
typedef unsigned int u32;
typedef __attribute__((ext_vector_type(8))) short bf8_t;   // 8 bf16 (4 VGPRs)
typedef __attribute__((ext_vector_type(4))) float f4_t;    // 4 fp32 acc

__device__ inline u16 f2b(float f) {
    __hip_bfloat16 h = __float2bfloat16(f);
    return __builtin_bit_cast(u16, h);
}

// async global->LDS, 16B per lane; LDS dest = uniform base + lane*16
#define GLD16(g, l) __builtin_amdgcn_global_load_lds( \
    (const __attribute__((address_space(1))) u32*)(g), \
    (__attribute__((address_space(3))) u32*)(l), 16, 0, 0)

#define MFMA16(a,b,c) __builtin_amdgcn_mfma_f32_16x16x32_bf16((a),(b),(c),0,0,0)

__device__ inline void cstore(float* p, float v) { *p = v; }
__device__ inline void cstore(u16* p, float v)   { *p = f2b(v); }

// ---------- fp32 -> bf16 elementwise ----------
__global__ void cvt_bf16_k(const float* __restrict__ in, u16* __restrict__ out, int n4) {
    int i = blockIdx.x * 256 + threadIdx.x;
    if (i < n4) {
        float4 v = ((const float4*)in)[i];
        u16* o = out + (size_t)i * 4;
        o[0] = f2b(v.x); o[1] = f2b(v.y); o[2] = f2b(v.z); o[3] = f2b(v.w);
    }
}

// ---------- W[K][N] fp32 -> WT[Npad][K] bf16 (zero-fill pad rows) ----------
__global__ void transpose_bf16_k(const float* __restrict__ W, u16* __restrict__ WT,
                                 int K, int N, int Npad) {
    __shared__ float t[32][33];
    int n0 = blockIdx.x * 32, k0 = blockIdx.y * 32;
    int tx = threadIdx.x, ty = threadIdx.y;  // 32 x 8
    for (int i = ty; i < 32; i += 8) {
        int n = n0 + tx;
        t[i][tx] = (n < N) ? W[(size_t)(k0 + i) * N + n] : 0.f;
    }
    __syncthreads();
    for (int i = ty; i < 32; i += 8) {
        int n = n0 + i;
        if (n < Npad) WT[(size_t)n * K + k0 + tx] = f2b(t[tx][i]);
    }
}

// ---------- MFMA GEMM: C(4096 x Nreal) = A(4096 x K, bf16) @ BT(Npad x K, bf16)^T ----------
// 128x128 block tile, BK=32, 4 waves (2x2), 4x4 of 16x16x32 per wave. m97 structure.
template <typename TO>
__global__ __launch_bounds__(256, 2)
void gemm_mfma(const u16* __restrict__ A, const u16* __restrict__ BT,
               TO* __restrict__ C, int K, int Nreal) {
    __shared__ u16 lA[128 * 32];
    __shared__ u16 lB[128 * 32];
    const int tid = threadIdx.x;
    const int w = tid >> 6, lane = tid & 63;
    const int quad = lane >> 4, col = lane & 15;
    const int wm = (w >> 1) * 64, wn = (w & 1) * 64;
    const int bm = blockIdx.y * 128, bn = blockIdx.x * 128;
    const int srow = lane >> 2;          // 0..15 row within 1KB chunk
    const int scol = (lane & 3) * 8;     // elem col within 32
    f4_t acc[4][4] = {};
    for (int k0 = 0; k0 < K; k0 += 32) {
        __syncthreads();
        #pragma unroll
        for (int cc = 0; cc < 2; cc++) {
            int c = 2 * w + cc;          // chunk 0..7 (16 rows each)
            int row = c * 16 + srow;
            GLD16(A  + (size_t)(bm + row) * K + k0 + scol, (char*)lA + c * 1024);
            GLD16(BT + (size_t)(bn + row) * K + k0 + scol, (char*)lB + c * 1024);
        }
        __syncthreads();
        bf8_t af[4], bf[4];
        #pragma unroll
        for (int i = 0; i < 4; i++) {
            af[i] = *(const bf8_t*)(lA + (wm + i * 16 + col) * 32 + quad * 8);
            bf[i] = *(const bf8_t*)(lB + (wn + i * 16 + col) * 32 + quad * 8);
        }
        #pragma unroll
        for (int mi = 0; mi < 4; mi++)
            #pragma unroll
            for (int ni = 0; ni < 4; ni++)
                acc[mi][ni] = MFMA16(af[mi], bf[ni], acc[mi][ni]);
    }
    #pragma unroll
    for (int mi = 0; mi < 4; mi++)
        #pragma unroll
        for (int ni = 0; ni < 4; ni++) {
            int n = bn + wn + ni * 16 + col;
            if (n < Nreal) {
                #pragma unroll
                for (int r = 0; r < 4; r++) {
                    int m = bm + wm + mi * 16 + quad * 4 + r;
                    cstore(C + (size_t)m * Nreal + n, acc[mi][ni][r]);
                }
            }
        }
}

// ---------- RMSNorm fp32 in -> bf16 out ----------
__global__ void rmsnorm_bf16_k(const float* __restrict__ in, int istride, int ncols,
                               const float* __restrict__ wt, u16* __restrict__ out, int ostride) {
    __shared__ float red[256];
    int row = blockIdx.x, tid = threadIdx.x;
    const float* rp = in + (size_t)row * istride;
    float s = 0.f;
    for (int c = tid; c < ncols; c += 256) { float v = rp[c]; s += v * v; }
    red[tid] = s;
    __syncthreads();
    for (int off = 128; off > 0; off >>= 1) {
        if (tid < off) red[tid] += red[tid + off];
        __syncthreads();
    }
    float sc = rsqrtf(red[0] / (float)ncols + EPSF);
    u16* op = out + (size_t)row * ostride;
    for (int c = tid; c < ncols; c += 256) op[c] = f2b(rp[c] * sc * wt[c]);
}

// ---------- RoPE on q + bf16 convert: q fp32 [tok][16][192] -> qb bf16 ----------
__global__ void rope_q_k(const float* __restrict__ q, u16* __restrict__ qb) {
    int idx = blockIdx.x;                 // tok*16 + h
    int pos = (idx >> 4) & (SS - 1);
    const float* src = q + (size_t)idx * 192;
    u16* dst = qb + (size_t)idx * 192;
    int t = threadIdx.x;                  // 64
    dst[t]      = f2b(src[t]);
    dst[t + 64] = f2b(src[t + 64]);
    if (t < 32) {
        float inv = powf(THETA, -(float)t * (1.0f / 32.0f));
        float ang = (float)pos * inv;
        float cs, sn; sincosf(ang, &sn, &cs);
        float x1 = src[128 + t], x2 = src[160 + t];
        dst[128 + t] = f2b(x1 * cs - x2 * sn);
        dst[160 + t] = f2b(x2 * cs + x1 * sn);
    }
}

// ---------- RoPE on k_pe: ckv fp32 [tok][576] cols 512.. -> kpe bf16 [tok][64] ----------
__global__ void rope_kpe_k(const float* __restrict__ ckv, u16* __restrict__ kpe) {
    int row = blockIdx.x;
    int pos = row & (SS - 1);
    int t = threadIdx.x;                  // 32
    float inv = powf(THETA, -(float)t * (1.0f / 32.0f));
    float ang = (float)pos * inv;
    float cs, sn; sincosf(ang, &sn, &cs);
    const float* pe = ckv + (size_t)row * 576 + 512;
    float x1 = pe[t], x2 = pe[t + 32];
    kpe[(size_t)row * 64 + t]      = f2b(x1 * cs - x2 * sn);
    kpe[(size_t)row * 64 + 32 + t] = f2b(x2 * cs + x1 * sn);
}

// ---------- Fused flash attention (MFMA, online softmax) ----------
// grid (32 bh, 32 qt), block 256 = 4 waves. Q-tile 64 (16 q/wave), K-tile 64.
// qb [tok][16][192] bf16; kvb [tok][16][256] (k_nope 0..127, v 128..255); kpe [tok][64].
__global__ __launch_bounds__(256, 2)
void attn_mfma(const u16* __restrict__ qb, const u16* __restrict__ kvb,
               const u16* __restrict__ kpe, u16* __restrict__ ob) {
    __shared__ u16 lK[64 * 200];   // K-tile [key][192], row stride 200 elems (400B)
    __shared__ u16 lV[128 * 72];   // V^T [dv][key], row stride 72 elems (144B)
    __shared__ u16 lP[4 * 16 * 72]; // per-wave P [16 q][64 key], stride 72
    const int tid = threadIdx.x, w = tid >> 6, lane = tid & 63;
    const int quad = lane >> 4, col = lane & 15;
    const int bh = blockIdx.x, b = bh >> 4, h = bh & 15;
    const int qt = 31 - (int)blockIdx.y;   // longest blocks first
    const int tok0 = b * SS;
    // Q fragments (A-operand): wave w owns queries qt*64 + w*16 + (0..15)
    bf8_t qf[6];
    {
        int qtok = tok0 + qt * 64 + w * 16 + col;
        const u16* qp = qb + ((size_t)qtok * HH + h) * 192 + quad * 8;
        #pragma unroll
        for (int kc = 0; kc < 6; kc++) qf[kc] = *(const bf8_t*)(qp + kc * 32);
    }
    f4_t o[8] = {};
    float mrow[4] = {-1e30f, -1e30f, -1e30f, -1e30f};
    float lrow[4] = {0.f, 0.f, 0.f, 0.f};
    const float SCL = 0.07216878364870322f * 1.4426950408889634f; // 1/sqrt(192)*log2e
    u16* pw = lP + w * 16 * 72;
    for (int kt = 0; kt <= qt; kt++) {
        int ktok = tok0 + kt * 64;
        __syncthreads();
        // stage K: 64 rows x 384B in stride-400B layout = 25 x 1KB chunks
        for (int c = w; c < 25; c += 4) {
            int o_b = c * 1024 + lane * 16;
            int row = o_b / 400;
            int ro  = o_b - row * 400;
            const u16* src;
            if (ro < 256)      src = kvb + ((size_t)(ktok + row) * HH + h) * 256 + (ro >> 1);
            else if (ro < 384) src = kpe + (size_t)(ktok + row) * 64 + ((ro - 256) >> 1);
            else               src = kpe;  // 16B pad slot, garbage OK (never read)
            GLD16(src, (char*)lK + c * 1024);
        }
        // stage V^T (key-major lanes: 2-way-free LDS writes)
        #pragma unroll
        for (int i = 0; i < 4; i++) {
            int dv8 = w + i * 4;           // 16B chunk of dv
            const u16* vp = kvb + ((size_t)(ktok + lane) * HH + h) * 256 + 128 + dv8 * 8;
            bf8_t vv = *(const bf8_t*)vp;
            #pragma unroll
            for (int j = 0; j < 8; j++) lV[(dv8 * 8 + j) * 72 + lane] = (u16)vv[j];
        }
        __syncthreads();
        // S = Q K^T  (contract d=192; identical k-addressing on both frags)
        f4_t s[4] = {};
        #pragma unroll
        for (int kc = 0; kc < 6; kc++) {
            #pragma unroll
            for (int t = 0; t < 4; t++) {
                bf8_t kf = *(const bf8_t*)(lK + (t * 16 + col) * 200 + kc * 32 + quad * 8);
                s[t] = MFMA16(qf[kc], kf, s[t]);
            }
        }
        // causal mask + scale + row max (row = query = quad*4+r, col = key)
        float sm[4] = {-1e30f, -1e30f, -1e30f, -1e30f};
        #pragma unroll
        for (int t = 0; t < 4; t++) {
            int kg = kt * 64 + t * 16 + col;
            #pragma unroll
            for (int r = 0; r < 4; r++) {
                int qg = qt * 64 + w * 16 + quad * 4 + r;
                float v = (kg <= qg) ? s[t][r] * SCL : -1e30f;
                s[t][r] = v;
                sm[r] = fmaxf(sm[r], v);
            }
        }
        #pragma unroll
        for (int off = 1; off < 16; off <<= 1)
            #pragma unroll
            for (int r = 0; r < 4; r++) sm[r] = fmaxf(sm[r], __shfl_xor(sm[r], off));
        float al[4];
        #pragma unroll
        for (int r = 0; r < 4; r++) {
            float mn = fmaxf(mrow[r], sm[r]);
            al[r] = exp2f(mrow[r] - mn);
            mrow[r] = mn;
        }
        float rs[4] = {0.f, 0.f, 0.f, 0.f};
        #pragma unroll
        for (int t = 0; t < 4; t++)
            #pragma unroll
            for (int r = 0; r < 4; r++) {
                float p = exp2f(s[t][r] - mrow[r]);
                s[t][r] = p;
                rs[r] += p;
            }
        #pragma unroll
        for (int off = 1; off < 16; off <<= 1)
            #pragma unroll
            for (int r = 0; r < 4; r++) rs[r] += __shfl_xor(rs[r], off);
        #pragma unroll
        for (int r = 0; r < 4; r++) lrow[r] = lrow[r] * al[r] + rs[r];
        #pragma unroll
        for (int n = 0; n < 8; n++)
            #pragma unroll
            for (int r = 0; r < 4; r++) o[n][r] *= al[r];
        // P (C-layout) -> wave-private LDS as bf16
        #pragma unroll
        for (int t = 0; t < 4; t++)
            #pragma unroll
            for (int r = 0; r < 4; r++)
                pw[(quad * 4 + r) * 72 + t * 16 + col] = f2b(s[t][r]);
        // O += P V  (P as A-frag from LDS, V^T as B-frag)
        #pragma unroll
        for (int kc2 = 0; kc2 < 2; kc2++) {
            bf8_t pf = *(const bf8_t*)(pw + col * 72 + kc2 * 32 + quad * 8);
            #pragma unroll
            for (int n = 0; n < 8; n++) {
                bf8_t vf = *(const bf8_t*)(lV + (n * 16 + col) * 72 + kc2 * 32 + quad * 8);
                o[n] = MFMA16(pf, vf, o[n]);
            }
        }
    }
    // store O / l  -> ob [tok][16][128] bf16
    #pragma unroll
    for (int n = 0; n < 8; n++)
        #pragma unroll
        for (int r = 0; r < 4; r++) {
            int qtok = tok0 + qt * 64 + w * 16 + quad * 4 + r;
            float v = o[n][r] / lrow[r];
            ob[((size_t)qtok * HH + h) * 128 + n * 16 + col] = f2b(v);
        }
}

extern "C" void kernel_launch(void* const* d_in, const int* in_sizes, int n_in,
                              void* d_out, int out_size, void* d_ws, size_t ws_size,
                              hipStream_t stream) {
    const float* x        = (const float*)d_in[0];
    const float* w_dq     = (const float*)d_in[1];
    const float* q_a_norm = (const float*)d_in[2];
    const float* w_uq     = (const float*)d_in[3];
    const float* w_dkv    = (const float*)d_in[4];
    const float* kv_a_nrm = (const float*)d_in[5];
    const float* w_ukv    = (const float*)d_in[6];
    const float* w_o      = (const float*)d_in[7];
    float* out = (float*)d_out;

    char* ws = (char*)d_ws;
    const size_t MB = 1024 * 1024;
    // Region map (peak 98MB; harness gives >=186MB):
    // [0,16MB)    xb (bf16 x)            -> later aob (attention out, bf16)
    // [16,25MB)   wT scratch (max 9MB, re-used per GEMM just-in-time)
    // [25,49MB)   q_lat fp32             -> later qb (rope'd q, bf16, 24MB)
    // [49,61MB)   qlb (bf16, 12MB)       -> later ckv fp32 (9MB)
    // [61,109MB)  q fp32 (48MB)          -> later ckvnb(4MB) | kpeb(0.5MB) | kvb(32MB)
    u16*   xb    = (u16*)(ws);
    u16*   wT    = (u16*)(ws + 16 * MB);
    float* qlat  = (float*)(ws + 25 * MB);
    u16*   qlb   = (u16*)(ws + 49 * MB);
    float* qf32  = (float*)(ws + 61 * MB);
    u16*   qbuf  = (u16*)(ws + 25 * MB);
    float* ckv   = (float*)(ws + 49 * MB);
    u16*   ckvnb = (u16*)(ws + 61 * MB);
    u16*   kpeb  = (u16*)(ws + 61 * MB + 4 * MB);
    u16*   kvb   = (u16*)(ws + 61 * MB + 5 * MB);
    u16*   aob   = (u16*)(ws);

    // 1. x -> bf16
    cvt_bf16_k<<<(MR * DDIM / 4 + 255) / 256, 256, 0, stream>>>(x, xb, MR * DDIM / 4);
    // 2. q_lat = x @ w_dq
    transpose_bf16_k<<<dim3(1536 / 32, 2048 / 32), dim3(32, 8), 0, stream>>>(w_dq, wT, 2048, 1536, 1536);
    gemm_mfma<float><<<dim3(1536 / 128, MR / 128), 256, 0, stream>>>(xb, wT, qlat, 2048, 1536);
    // 3. rmsnorm(q_lat) -> bf16
    rmsnorm_bf16_k<<<MR, 256, 0, stream>>>(qlat, QR, QR, q_a_norm, qlb, QR);
    // 4. q = qlb @ w_uq
    transpose_bf16_k<<<dim3(3072 / 32, 1536 / 32), dim3(32, 8), 0, stream>>>(w_uq, wT, 1536, 3072, 3072);
    gemm_mfma<float><<<dim3(3072 / 128, MR / 128), 256, 0, stream>>>(qlb, wT, qf32, 1536, 3072);
    // 5. rope(q) -> bf16 qbuf
    rope_q_k<<<MR * HH, 64, 0, stream>>>(qf32, qbuf);
    // 6. ckv = x @ w_dkv  (N=576 padded to 640)
    transpose_bf16_k<<<dim3(640 / 32, 2048 / 32), dim3(32, 8), 0, stream>>>(w_dkv, wT, 2048, 576, 640);
    gemm_mfma<float><<<dim3(640 / 128, MR / 128), 256, 0, stream>>>(xb, wT, ckv, 2048, 576);
    // 7. rmsnorm(ckv[:, :512]) -> bf16
    rmsnorm_bf16_k<<<MR, 256, 0, stream>>>(ckv, 576, KVR, kv_a_nrm, ckvnb, KVR);
    // 8. rope(k_pe) -> bf16
    rope_kpe_k<<<MR, 32, 0, stream>>>(ckv, kpeb);
    // 9. kv = ckvnb @ w_ukv -> bf16 [tok][16][256]
    transpose_bf16_k<<<dim3(4096 / 32, 512 / 32), dim3(32, 8), 0, stream>>>(w_ukv, wT, 512, 4096, 4096);
    gemm_mfma<u16><<<dim3(4096 / 128, MR / 128), 256, 0, stream>>>(ckvnb, wT, kvb, 512, 4096);
    // 10. fused flash attention -> aob bf16 [tok][16][128]
    attn_mfma<<<dim3(32, 32), 256, 0, stream>>>(qbuf, kvb, kpeb, aob);
    // 11. out = aob @ w_o
    transpose_bf16_k<<<dim3(2048 / 32, 2048 / 32), dim3(32, 8), 0, stream>>>(w_o, wT, 2048, 2048, 2048);
    gemm_mfma<float><<<dim3(2048 / 128, MR / 128), 256, 0, stream>>>(aob, wT, out, 2048, 2048);
}

// Round 4
// 461.974 us; speedup vs baseline: 25.9382x; 1.1693x over previous
//
#include <hip/hip_runtime.h>
#include <hip/hip_bf16.h>
#include <math.h>

#define SS 2048
#define HH 16
#define EPSF 1e-6f
#define MR 4096              // tokens
#define L2T 13.287712379549449f   // log2(10000)
// 1/sqrt(192) * log2(e), folded into q at G2 epilogue
#define ASCL (0.07216878364870322f * 1.4426950408889634f)

typedef unsigned short u16;
typedef unsigned int u32;
typedef __attribute__((ext_vector_type(8))) short bf8_t;
typedef __attribute__((ext_vector_type(4))) float f4_t;

__device__ inline u16 f2b(float f) {
    __hip_bfloat16 h = __float2bfloat16(f);
    return __builtin_bit_cast(u16, h);
}
__device__ inline float b2f(u16 x) {
    u32 v = (u32)x << 16;
    return __builtin_bit_cast(float, v);
}

#define GLD16(g, l) __builtin_amdgcn_global_load_lds( \
    (const __attribute__((address_space(1))) u32*)(g), \
    (__attribute__((address_space(3))) u32*)(l), 16, 0, 0)

#define MFMA16(a,b,c) __builtin_amdgcn_mfma_f32_16x16x32_bf16((a),(b),(c),0,0,0)

// ================= prep: x->bf16 cvt + all 5 weight transposes =================
__global__ void prep_k(const float* __restrict__ x, u16* __restrict__ xb,
                       const float* __restrict__ w_dq, const float* __restrict__ w_dkv,
                       const float* __restrict__ w_uq, const float* __restrict__ w_ukv,
                       const float* __restrict__ w_o,
                       u16* __restrict__ wT1, u16* __restrict__ wTuq,
                       u16* __restrict__ wTukv, u16* __restrict__ wTo) {
    __shared__ float tt[32][33];
    int blk = blockIdx.x, tid = threadIdx.x;
    if (blk < 8192) {                       // x conversion: 4096x2048 fp32 -> bf16
        int i = blk * 256 + tid;
        float4 v = ((const float4*)x)[i];
        ushort4 o;
        o.x = f2b(v.x); o.y = f2b(v.y); o.z = f2b(v.z); o.w = f2b(v.w);
        *(ushort4*)(xb + (size_t)i * 4) = o;
        return;
    }
    blk -= 8192;
    const float* W; u16* dst; int K, N, Npad, nx;
    if (blk < 3072)       { W = w_dq;  dst = wT1;                      K = 2048; N = 1536; Npad = 1536; nx = 48; }
    else if (blk < 4352)  { blk -= 3072; W = w_dkv; dst = wT1 + (size_t)1536 * 2048; K = 2048; N = 576;  Npad = 640;  nx = 20; }
    else if (blk < 8960)  { blk -= 4352; W = w_uq;  dst = wTuq;        K = 1536; N = 3072; Npad = 3072; nx = 96; }
    else if (blk < 11008) { blk -= 8960; W = w_ukv; dst = wTukv;       K = 512;  N = 4096; Npad = 4096; nx = 128; }
    else                  { blk -= 11008; W = w_o;  dst = wTo;         K = 2048; N = 2048; Npad = 2048; nx = 64; }
    int n0 = (blk % nx) * 32, k0 = (blk / nx) * 32;
    int tx = tid & 31, ty = tid >> 5;
    for (int i = ty; i < 32; i += 8) {
        int n = n0 + tx;
        tt[i][tx] = (n < N) ? W[(size_t)(k0 + i) * N + n] : 0.f;
    }
    __syncthreads();
    for (int i = ty; i < 32; i += 8) {
        int n = n0 + i;
        if (n < Npad) dst[(size_t)n * K + k0 + tx] = f2b(tt[tx][i]);
    }
}

// ================= MFMA GEMM (m97 structure), templated epilogue =================
// MODE 0: fp32 out; MODE 1: bf16 out; MODE 2: bf16 out + fused RoPE + ASCL (q path)
template <int MODE>
__global__ __launch_bounds__(256, 2)
void gemm_mfma(const u16* __restrict__ A, const u16* __restrict__ BT,
               void* __restrict__ Cv, int K, int N) {
    __shared__ u16 lA[128 * 32];
    __shared__ u16 lB[128 * 32];
    const int tid = threadIdx.x;
    const int w = tid >> 6, lane = tid & 63;
    const int quad = lane >> 4, col = lane & 15;
    const int wm = (w >> 1) * 64, wn = (w & 1) * 64;
    const int bm = blockIdx.y * 128, bn = blockIdx.x * 128;
    const int srow = lane >> 2;
    const int scol = (lane & 3) * 8;
    f4_t acc[4][4] = {};
    for (int k0 = 0; k0 < K; k0 += 32) {
        __syncthreads();
        #pragma unroll
        for (int cc = 0; cc < 2; cc++) {
            int c = 2 * w + cc;
            int row = c * 16 + srow;
            GLD16(A  + (size_t)(bm + row) * K + k0 + scol, (char*)lA + c * 1024);
            GLD16(BT + (size_t)(bn + row) * K + k0 + scol, (char*)lB + c * 1024);
        }
        __syncthreads();
        bf8_t af[4], bf[4];
        #pragma unroll
        for (int i = 0; i < 4; i++) {
            af[i] = *(const bf8_t*)(lA + (wm + i * 16 + col) * 32 + quad * 8);
            bf[i] = *(const bf8_t*)(lB + (wn + i * 16 + col) * 32 + quad * 8);
        }
        #pragma unroll
        for (int mi = 0; mi < 4; mi++)
            #pragma unroll
            for (int ni = 0; ni < 4; ni++)
                acc[mi][ni] = MFMA16(af[mi], bf[ni], acc[mi][ni]);
    }
    if (MODE == 0) {
        float* C = (float*)Cv;
        #pragma unroll
        for (int mi = 0; mi < 4; mi++)
            #pragma unroll
            for (int ni = 0; ni < 4; ni++) {
                int n = bn + wn + ni * 16 + col;
                #pragma unroll
                for (int r = 0; r < 4; r++) {
                    int m = bm + wm + mi * 16 + quad * 4 + r;
                    C[(size_t)m * N + n] = acc[mi][ni][r];
                }
            }
    } else if (MODE == 1) {
        u16* C = (u16*)Cv;
        #pragma unroll
        for (int mi = 0; mi < 4; mi++)
            #pragma unroll
            for (int ni = 0; ni < 4; ni++) {
                int n = bn + wn + ni * 16 + col;
                #pragma unroll
                for (int r = 0; r < 4; r++) {
                    int m = bm + wm + mi * 16 + quad * 4 + r;
                    C[(size_t)m * N + n] = f2b(acc[mi][ni][r]);
                }
            }
    } else {
        u16* C = (u16*)Cv;
        int span = ((bn + wn) >> 6) % 3;      // 0,1: nope span; 2: pe span (64-aligned)
        if (span < 2) {
            #pragma unroll
            for (int mi = 0; mi < 4; mi++)
                #pragma unroll
                for (int ni = 0; ni < 4; ni++) {
                    int n = bn + wn + ni * 16 + col;
                    #pragma unroll
                    for (int r = 0; r < 4; r++) {
                        int m = bm + wm + mi * 16 + quad * 4 + r;
                        C[(size_t)m * N + n] = f2b(acc[mi][ni][r] * ASCL);
                    }
                }
        } else {
            #pragma unroll
            for (int ni = 0; ni < 2; ni++) {
                int e = ni * 16 + col;        // rope dim 0..31
                float inv = exp2f(-(float)e * (L2T / 32.0f));
                #pragma unroll
                for (int mi = 0; mi < 4; mi++) {
                    #pragma unroll
                    for (int r = 0; r < 4; r++) {
                        int m = bm + wm + mi * 16 + quad * 4 + r;
                        int pos = m & (SS - 1);
                        float ang = (float)pos * inv;
                        float cs, sn; sincosf(ang, &sn, &cs);
                        float x1 = acc[mi][ni][r], x2 = acc[mi][ni + 2][r];
                        int n = bn + wn + ni * 16 + col;
                        C[(size_t)m * N + n]      = f2b((x1 * cs - x2 * sn) * ASCL);
                        C[(size_t)m * N + n + 32] = f2b((x2 * cs + x1 * sn) * ASCL);
                    }
                }
            }
        }
    }
}

// ================= RMSNorm q: C1[:, :1536] bf16 -> qlb bf16 =================
__global__ void rmsq_k(const u16* __restrict__ C1, const float* __restrict__ wt,
                       u16* __restrict__ qlb) {
    __shared__ float red[256];
    int row = blockIdx.x, tid = threadIdx.x;
    const ushort4* rp = (const ushort4*)(C1 + (size_t)row * 2176);
    float s = 0.f;
    for (int i = tid; i < 384; i += 256) {
        ushort4 u = rp[i];
        float a = b2f(u.x), b = b2f(u.y), c = b2f(u.z), d = b2f(u.w);
        s += a * a + b * b + c * c + d * d;
    }
    red[tid] = s;
    __syncthreads();
    for (int off = 128; off > 0; off >>= 1) {
        if (tid < off) red[tid] += red[tid + off];
        __syncthreads();
    }
    float sc = rsqrtf(red[0] * (1.0f / 1536.0f) + EPSF);
    ushort4* op = (ushort4*)(qlb + (size_t)row * 1536);
    const float4* wv = (const float4*)wt;
    for (int i = tid; i < 384; i += 256) {
        ushort4 u = rp[i];
        float4 ww = wv[i];
        ushort4 o;
        o.x = f2b(b2f(u.x) * sc * ww.x);
        o.y = f2b(b2f(u.y) * sc * ww.y);
        o.z = f2b(b2f(u.z) * sc * ww.z);
        o.w = f2b(b2f(u.w) * sc * ww.w);
        op[i] = o;
    }
}

// ============ RMSNorm kv (C1 cols 1536..2047) + RoPE k_pe (cols 2048..2111) ============
__global__ void rmskv_rope_k(const u16* __restrict__ C1, const float* __restrict__ wt,
                             u16* __restrict__ ckvnb, u16* __restrict__ kpeb) {
    __shared__ float red[256];
    int row = blockIdx.x, tid = threadIdx.x;
    const u16* base = C1 + (size_t)row * 2176 + 1536;
    if (tid < 32) {   // rope on k_pe (independent of rms)
        int t = tid;
        float x1 = b2f(base[512 + t]), x2 = b2f(base[544 + t]);
        int pos = row & (SS - 1);
        float inv = exp2f(-(float)t * (L2T / 32.0f));
        float ang = (float)pos * inv;
        float cs, sn; sincosf(ang, &sn, &cs);
        kpeb[(size_t)row * 64 + t]      = f2b(x1 * cs - x2 * sn);
        kpeb[(size_t)row * 64 + 32 + t] = f2b(x2 * cs + x1 * sn);
    }
    const ushort4* rp = (const ushort4*)base;
    float s = 0.f;
    if (tid < 128) {
        ushort4 u = rp[tid];
        float a = b2f(u.x), b = b2f(u.y), c = b2f(u.z), d = b2f(u.w);
        s = a * a + b * b + c * c + d * d;
    }
    red[tid] = s;
    __syncthreads();
    for (int off = 128; off > 0; off >>= 1) {
        if (tid < off) red[tid] += red[tid + off];
        __syncthreads();
    }
    float sc = rsqrtf(red[0] * (1.0f / 512.0f) + EPSF);
    if (tid < 128) {
        ushort4 u = rp[tid];
        float4 ww = ((const float4*)wt)[tid];
        ushort4 o;
        o.x = f2b(b2f(u.x) * sc * ww.x);
        o.y = f2b(b2f(u.y) * sc * ww.y);
        o.z = f2b(b2f(u.z) * sc * ww.z);
        o.w = f2b(b2f(u.w) * sc * ww.w);
        ((ushort4*)(ckvnb + (size_t)row * 512))[tid] = o;
    }
}

// ================= Fused flash attention (paired Q-tiles, balanced) =================
// grid (32 bh, 16 pairs), block 256 = 4 waves. Q pre-scaled by 1/sqrt(192)*log2e.
__global__ __launch_bounds__(256, 3)
void attn_mfma(const u16* __restrict__ qb, const u16* __restrict__ kvb,
               const u16* __restrict__ kpe, u16* __restrict__ ob) {
    __shared__ u16 lK[64 * 200];     // [key][192+pad], 400B rows
    __shared__ u16 lV[128 * 72];     // V^T [dv][key], 144B rows
    __shared__ u16 lP[4 * 16 * 80];  // per-wave P [16 q][64 key], 160B rows
    const int tid = threadIdx.x, w = tid >> 6, lane = tid & 63;
    const int quad = lane >> 4, col = lane & 15;
    const int bh = blockIdx.x, b = bh >> 4, h = bh & 15;
    const int tok0 = b * SS;
    // precompute K-staging per-lane offsets (kt-independent)
    int offE[7], isKV[7];
    #pragma unroll
    for (int jj = 0; jj < 7; jj++) {
        int c = w + 4 * jj;
        int o_b = c * 1024 + lane * 16;
        int row = o_b / 400;
        int ro = o_b - row * 400;
        if (ro < 256)      { offE[jj] = (row * 16 + h) * 256 + (ro >> 1); isKV[jj] = 1; }
        else if (ro < 384) { offE[jj] = row * 64 + ((ro - 256) >> 1);     isKV[jj] = 0; }
        else               { offE[jj] = 0;                                 isKV[jj] = 0; }
    }
    const int kp2 = lane & 31, dh = lane >> 5;
    u16* pw = lP + w * 16 * 80;

    for (int ph = 0; ph < 2; ph++) {
        const int qt = ph ? (31 - (int)blockIdx.y) : (int)blockIdx.y;
        bf8_t qf[6];
        {
            int qtok = tok0 + qt * 64 + w * 16 + col;
            const u16* qp = qb + ((size_t)qtok * HH + h) * 192 + quad * 8;
            #pragma unroll
            for (int kc = 0; kc < 6; kc++) qf[kc] = *(const bf8_t*)(qp + kc * 32);
        }
        f4_t o[8] = {};
        float mrow[4] = {-1e30f, -1e30f, -1e30f, -1e30f};
        float lrow[4] = {0.f, 0.f, 0.f, 0.f};
        for (int kt = 0; kt <= qt; kt++) {
            int ktok = tok0 + kt * 64;
            __syncthreads();
            // K stage: 25 x 1KB chunks
            #pragma unroll
            for (int jj = 0; jj < 7; jj++) {
                int c = w + 4 * jj;
                if (c < 25) {
                    const u16* src = isKV[jj] ? kvb + (size_t)ktok * 4096 + offE[jj]
                                              : kpe + (size_t)ktok * 64   + offE[jj];
                    GLD16(src, (char*)lK + c * 1024);
                }
            }
            // V^T stage: key-pair packed b32 writes (conflict-free)
            #pragma unroll
            for (int i = 0; i < 2; i++) {
                int dv8 = w * 4 + dh * 2 + i;
                const u16* v0 = kvb + ((size_t)(ktok + 2 * kp2) * HH + h) * 256 + 128 + dv8 * 8;
                uint4 a4 = *(const uint4*)v0;
                uint4 b4 = *(const uint4*)(v0 + 4096);
                u32 av[4] = {a4.x, a4.y, a4.z, a4.w};
                u32 bv[4] = {b4.x, b4.y, b4.z, b4.w};
                u32* dst = (u32*)lV + (size_t)(dv8 * 8) * 36 + kp2;
                #pragma unroll
                for (int t = 0; t < 4; t++) {
                    u32 lo = __builtin_amdgcn_perm(bv[t], av[t], 0x05040100u);
                    u32 hi = __builtin_amdgcn_perm(bv[t], av[t], 0x07060302u);
                    dst[(2 * t) * 36]     = lo;
                    dst[(2 * t + 1) * 36] = hi;
                }
            }
            __syncthreads();
            bool diag = (kt == qt);
            f4_t s[4] = {};
            #pragma unroll
            for (int t = 0; t < 4; t++) {
                if (!diag || t <= w) {
                    #pragma unroll
                    for (int kc = 0; kc < 6; kc++) {
                        bf8_t kf = *(const bf8_t*)(lK + (t * 16 + col) * 200 + kc * 32 + quad * 8);
                        s[t] = MFMA16(qf[kc], kf, s[t]);
                    }
                }
            }
            if (diag) {
                #pragma unroll
                for (int t = 0; t < 4; t++) {
                    int kg = t * 16 + col;
                    #pragma unroll
                    for (int r = 0; r < 4; r++) {
                        int qg = w * 16 + quad * 4 + r;
                        if (kg > qg) s[t][r] = -1e30f;
                    }
                }
            }
            float sm[4] = {-1e30f, -1e30f, -1e30f, -1e30f};
            #pragma unroll
            for (int t = 0; t < 4; t++)
                #pragma unroll
                for (int r = 0; r < 4; r++) sm[r] = fmaxf(sm[r], s[t][r]);
            #pragma unroll
            for (int off = 1; off < 16; off <<= 1)
                #pragma unroll
                for (int r = 0; r < 4; r++) sm[r] = fmaxf(sm[r], __shfl_xor(sm[r], off));
            float al[4];
            #pragma unroll
            for (int r = 0; r < 4; r++) {
                float mn = fmaxf(mrow[r], sm[r]);
                al[r] = exp2f(mrow[r] - mn);
                mrow[r] = mn;
            }
            float rs[4] = {0.f, 0.f, 0.f, 0.f};
            #pragma unroll
            for (int t = 0; t < 4; t++)
                #pragma unroll
                for (int r = 0; r < 4; r++) {
                    float p = exp2f(s[t][r] - mrow[r]);
                    s[t][r] = p;
                    rs[r] += p;
                }
            #pragma unroll
            for (int off = 1; off < 16; off <<= 1)
                #pragma unroll
                for (int r = 0; r < 4; r++) rs[r] += __shfl_xor(rs[r], off);
            #pragma unroll
            for (int r = 0; r < 4; r++) lrow[r] = lrow[r] * al[r] + rs[r];
            #pragma unroll
            for (int n = 0; n < 8; n++)
                #pragma unroll
                for (int r = 0; r < 4; r++) o[n][r] *= al[r];
            #pragma unroll
            for (int t = 0; t < 4; t++)
                #pragma unroll
                for (int r = 0; r < 4; r++)
                    pw[(quad * 4 + r) * 80 + t * 16 + col] = f2b(s[t][r]);
            #pragma unroll
            for (int kc2 = 0; kc2 < 2; kc2++) {
                bf8_t pf = *(const bf8_t*)(pw + col * 80 + kc2 * 32 + quad * 8);
                #pragma unroll
                for (int n = 0; n < 8; n++) {
                    bf8_t vf = *(const bf8_t*)(lV + (n * 16 + col) * 72 + kc2 * 32 + quad * 8);
                    o[n] = MFMA16(pf, vf, o[n]);
                }
            }
        }
        #pragma unroll
        for (int n = 0; n < 8; n++)
            #pragma unroll
            for (int r = 0; r < 4; r++) {
                int qtok = tok0 + qt * 64 + w * 16 + quad * 4 + r;
                ob[((size_t)qtok * HH + h) * 128 + n * 16 + col] = f2b(o[n][r] / lrow[r]);
            }
    }
}

extern "C" void kernel_launch(void* const* d_in, const int* in_sizes, int n_in,
                              void* d_out, int out_size, void* d_ws, size_t ws_size,
                              hipStream_t stream) {
    const float* x        = (const float*)d_in[0];
    const float* w_dq     = (const float*)d_in[1];
    const float* q_a_norm = (const float*)d_in[2];
    const float* w_uq     = (const float*)d_in[3];
    const float* w_dkv    = (const float*)d_in[4];
    const float* kv_a_nrm = (const float*)d_in[5];
    const float* w_ukv    = (const float*)d_in[6];
    const float* w_o      = (const float*)d_in[7];
    float* out = (float*)d_out;

    char* ws = (char*)d_ws;
    const size_t MB = 1024 * 1024;
    u16* xb    = (u16*)(ws);             // 16.8MB ; reused later as aob
    u16* wT1   = (u16*)(ws + 17 * MB);   // [2176][2048] dq^T + dkv^T(pad640) : 8.9MB
    u16* wTuq  = (u16*)(ws + 26 * MB);   // [3072][1536] : 9.4MB
    u16* wTukv = (u16*)(ws + 36 * MB);   // [4096][512]  : 4.2MB
    u16* wTo   = (u16*)(ws + 41 * MB);   // [2048][2048] : 8.4MB
    u16* C1    = (u16*)(ws + 50 * MB);   // [4096][2176] qlat|ckv|kpe : 17.8MB
    u16* qlb   = (u16*)(ws + 68 * MB);   // [4096][1536] : 12.6MB
    u16* qbuf  = (u16*)(ws + 81 * MB);   // [4096][3072] : 25.2MB
    u16* ckvnb = (u16*)(ws + 106 * MB);  // [4096][512]  : 4.2MB
    u16* kpeb  = (u16*)(ws + 110 * MB);  // [4096][64]   : 0.5MB
    u16* kvb   = (u16*)(ws + 111 * MB);  // [4096][16][256] : 33.6MB (ends 144MB)
    u16* aob   = xb;

    // 1. prep: x->bf16 + all weight transposes (one launch)
    prep_k<<<23296, 256, 0, stream>>>(x, xb, w_dq, w_dkv, w_uq, w_ukv, w_o,
                                      wT1, wTuq, wTukv, wTo);
    // 2. C1 = x @ [w_dq | w_dkv]  (N=2176), bf16 out
    gemm_mfma<1><<<dim3(17, 32), 256, 0, stream>>>(xb, wT1, C1, 2048, 2176);
    // 3. rmsnorm q latent
    rmsq_k<<<MR, 256, 0, stream>>>(C1, q_a_norm, qlb);
    // 4. q = qlb @ w_uq with fused RoPE + attention scale, bf16 out
    gemm_mfma<2><<<dim3(24, 32), 256, 0, stream>>>(qlb, wTuq, qbuf, 1536, 3072);
    // 5. rmsnorm kv latent + rope k_pe
    rmskv_rope_k<<<MR, 256, 0, stream>>>(C1, kv_a_nrm, ckvnb, kpeb);
    // 6. kv = ckvnb @ w_ukv, bf16 out [tok][16][256]
    gemm_mfma<1><<<dim3(32, 32), 256, 0, stream>>>(ckvnb, wTukv, kvb, 512, 4096);
    // 7. fused flash attention (paired Q-tiles for load balance)
    attn_mfma<<<dim3(32, 16), 256, 0, stream>>>(qbuf, kvb, kpeb, aob);
    // 8. out = aob @ w_o, fp32 out
    gemm_mfma<0><<<dim3(16, 32), 256, 0, stream>>>(aob, wTo, out, 2048, 2048);
}